// Round 14
// baseline (198.903 us; speedup 1.0000x reference)
//
#include <hip/hip_runtime.h>
#include <stdint.h>

typedef _Float16 half8 __attribute__((ext_vector_type(8)));
typedef _Float16 half4v __attribute__((ext_vector_type(4)));
typedef float floatx4 __attribute__((ext_vector_type(4)));
typedef float floatx16 __attribute__((ext_vector_type(16)));

#define TT 4096
#define DH 512

#define WAITLGKM() asm volatile("s_waitcnt lgkmcnt(0)" ::: "memory")
#define BAR() __builtin_amdgcn_s_barrier()
#define FENCE() asm volatile("" ::: "memory")

__device__ __forceinline__ unsigned short f2h(float f) {
    union { _Float16 h; unsigned short u; } v;
    v.h = (_Float16)f;
    return v.u;
}

// ---------- kernel 1: normalize right half of x -> xn (fp16), one wave per row ----------
__global__ void norm_k(const float* __restrict__ x, unsigned short* __restrict__ xn) {
    const int w = threadIdx.x >> 6, l = threadIdx.x & 63;
    const int row = blockIdx.x * 4 + w;              // 0 .. B*T-1
    const float* src = x + (size_t)row * 1024 + 512 + l * 8;
    floatx4 a = *(const floatx4*)src;
    floatx4 c = *(const floatx4*)(src + 4);
    float s = a[0]*a[0] + a[1]*a[1] + a[2]*a[2] + a[3]*a[3]
            + c[0]*c[0] + c[1]*c[1] + c[2]*c[2] + c[3]*c[3];
    #pragma unroll
    for (int off = 32; off > 0; off >>= 1) s += __shfl_xor(s, off);
    const float scale = 1.0f / fmaxf(sqrtf(s), 1e-12f);
    float v[8] = {a[0], a[1], a[2], a[3], c[0], c[1], c[2], c[3]};
    uint32_t pk[4];
    #pragma unroll
    for (int i = 0; i < 4; i++)
        pk[i] = (uint32_t)f2h(v[2*i] * scale) | ((uint32_t)f2h(v[2*i+1] * scale) << 16);
    uint4 o; o.x = pk[0]; o.y = pk[1]; o.z = pk[2]; o.w = pk[3];
    *(uint4*)(xn + (size_t)row * DH + l * 8) = o;
}

// ---------- kernel 2: xnT[b][d][t] = xn[b][t][d], 64x64 LDS tile transpose ----------
__global__ void transpose_k(const unsigned short* __restrict__ xn,
                            unsigned short* __restrict__ xnT) {
    __shared__ __align__(16) unsigned short tile[64 * 72];  // +8 pad
    const int b = blockIdx.z;
    const int t0 = blockIdx.x * 64, d0 = blockIdx.y * 64;
    const int tid = threadIdx.x;
    #pragma unroll
    for (int i = 0; i < 2; i++) {
        int c = i * 256 + tid;
        int tr = c >> 3, d8 = c & 7;
        uint4 vv = *(const uint4*)(xn + ((size_t)(b * TT + t0 + tr) * DH + d0 + d8 * 8));
        *(uint4*)&tile[tr * 72 + d8 * 8] = vv;
    }
    __syncthreads();
    #pragma unroll
    for (int i = 0; i < 2; i++) {
        int c = i * 256 + tid;
        int dd = c >> 3, t8 = c & 7;
        uint32_t pk[4];
        #pragma unroll
        for (int k = 0; k < 4; k++) {
            uint32_t h0 = tile[(t8 * 8 + 2 * k    ) * 72 + dd];
            uint32_t h1 = tile[(t8 * 8 + 2 * k + 1) * 72 + dd];
            pk[k] = h0 | (h1 << 16);
        }
        uint4 o; o.x = pk[0]; o.y = pk[1]; o.z = pk[2]; o.w = pk[3];
        *(uint4*)(xnT + ((size_t)(b * DH + d0 + dd) * TT + t0 + t8 * 8)) = o;
    }
}

// ---------- kernel 3: R13 schedule + 4-bit XOR Sred/W keys (all-b64, conflict-free) ----------
// Wave w: step1 role (g=w>>2, mi=(w>>1)&1, dh=w&1): S^T partial p=g*2+dh over K=128;
//   step3/epilogue role: d-slice [w*64, w*64+64).
// Sred/W unit mapping: logical unit u (4 halfs) of row q stored at phys = u ^ (q & 15).
// All Sred/W traffic is b64-granular -> every access class 2-way or inherent (free).
// Per tile (3 barriers):
//   vmcnt(10) ; step1 (8 rd, 16 mfma) ; Sred wr (b64) ; issue kn[t+1] ; lgkm ; BAR_B
//   reduce (8 b64 rd) ; vmcnt(8) ; *V ; W wr to OWN addrs (b64, bijection) ; lgkm ; BAR_C
//   step3 (16 b64 W rd + 8 b128 kt rd, 16 mfma) ; issue kt[t+1]+V[t+1] ; lgkm ; BAR_D
// LDS 160 KiB exact: kn[8w][32kk][128d] 64K | kt[8w][64d][64kk] 64K | Sred[4][64][64] 32K (p0=W).
__global__ __launch_bounds__(512, 2) void fused_k(
    const unsigned short* __restrict__ xn, const unsigned short* __restrict__ xnT,
    const float* __restrict__ V, const float* __restrict__ bias,
    const float* __restrict__ x, float* __restrict__ out)
{
    __shared__ __align__(16) unsigned short smem[81920];   // 160 KiB exact
    unsigned short* knB   = smem;            // [8 w][32 kk][128 d], chunk16 ^ (row&15)
    unsigned short* ktB   = smem + 32768;    // [8 w][64 d][64 kk], chunk16 ^ (row&7)
    unsigned short* SredL = smem + 65536;    // [4 p][64 q][16 units], unit ^ (q&15); p0 = W

    const int tid = threadIdx.x;
    const int w = tid >> 6, l = tid & 63;
    const int h = l >> 5, m32 = l & 31;
    const int g = w >> 2, mi = (w >> 1) & 1, dh = w & 1;
    const int p = g * 2 + dh;
    const int wk0 = g * 256 + dh * 128;      // step1 k-range base
    const int wd0 = w * 64;                  // step3 d-slice base

    // XCD-aware swizzle
    const int flat = blockIdx.y * 64 + blockIdx.x;
    const int work = (flat & 7) * 32 + (flat >> 3);
    const int b = work >> 6, qt = work & 63;
    const int q0 = qt * 64;

    const unsigned short* xnb = xn  + (size_t)b * TT * DH;
    const unsigned short* xtb = xnT + (size_t)b * DH * TT;

    unsigned short* knP = knB + w * 4096;
    unsigned short* ktP = ktB + w * 4096;

    // reduce-phase mapping: q-row tq, kk chunk to (logical units 2to, 2to+1)
    const int tq = tid >> 3, to = tid & 7;
    const float* vptr = V + (size_t)(q0 + tq) * TT + to * 8;
    const int keyR = tq & 15;
    const int aLo = ((to * 2    ) ^ keyR) * 4;   // phys half-offset of logical unit 2to
    const int aHi = ((to * 2 + 1) ^ keyR) * 4;   // phys half-offset of logical unit 2to+1

    // ---- prologue: Q fragments (B-operand): lane q=q0+ni*32+m32, k=wk0+ks*16+h*8+j
    half8 qf[2][8];
    #pragma unroll
    for (int ni = 0; ni < 2; ni++)
        #pragma unroll
        for (int ks = 0; ks < 8; ks++)
            qf[ni][ks] = *(const half8*)(xnb + (size_t)(q0 + ni*32 + m32) * DH
                                         + wk0 + ks*16 + h*8);
    FENCE();
    // stage kn[0]: 8 gll, 4 rows each; 16-key pre-swizzle at source
    #pragma unroll
    for (int i = 0; i < 8; i++) {
        int r = i * 4 + (l >> 4);                        // local kk row 0..31
        int c = (l & 15) ^ (r & 15);                     // pre-swizzled global chunk
        const unsigned short* gp = xnb + (size_t)(mi*32 + r) * DH + wk0 + c * 8;
        __builtin_amdgcn_global_load_lds(
            (const __attribute__((address_space(1))) void*)gp,
            (__attribute__((address_space(3))) void*)&knP[i * 512], 16, 0, 0);
    }
    FENCE();
    // stage kt[0]: 8 gll, 8 d-rows each
    #pragma unroll
    for (int i = 0; i < 8; i++) {
        int dr = i * 8 + (l >> 3);                       // local d row 0..63
        int c = (l & 7) ^ (dr & 7);
        const unsigned short* gp = xtb + (size_t)(wd0 + dr) * TT + c * 8;
        __builtin_amdgcn_global_load_lds(
            (const __attribute__((address_space(1))) void*)gp,
            (__attribute__((address_space(3))) void*)&ktP[i * 512], 16, 0, 0);
    }
    FENCE();
    floatx4 vf0 = *(const floatx4*)(vptr);
    floatx4 vf1 = *(const floatx4*)(vptr + 4);

    floatx16 acc[2][2];
    #pragma unroll
    for (int i = 0; i < 2; i++)
        #pragma unroll
        for (int j = 0; j < 2; j++)
            acc[i][j] = (floatx16)(0.f);

    #pragma unroll 1
    for (int t = 0; t < 64; t++) {
        // ---- kn[t] landed (kt[t] 8 + V[t] 2 stay in flight) ----
        asm volatile("s_waitcnt vmcnt(10)" ::: "memory");

        // ---- step1: S^T partial p, rows mi, k-128; 8 reads (2-way max), 16 mfma ----
        floatx16 s0 = (floatx16)(0.f), s1 = (floatx16)(0.f);
        __builtin_amdgcn_s_setprio(1);
        #pragma unroll
        for (int ks = 0; ks < 8; ks++) {
            half8 a = *(const half8*)&knP[m32 * 128 + (((ks*2 + h) ^ (m32 & 15)) * 8)];
            s0 = __builtin_amdgcn_mfma_f32_32x32x16_f16(a, qf[0][ks], s0, 0, 0, 0);
            s1 = __builtin_amdgcn_mfma_f32_32x32x16_f16(a, qf[1][ks], s1, 0, 0, 0);
        }
        __builtin_amdgcn_s_setprio(0);

        // ---- Sred write: [p][q][unit u ^ (q&15)], b64 (2-way free) ----
        #pragma unroll
        for (int ni = 0; ni < 2; ni++) {
            const int q = ni * 32 + m32;
            unsigned short* sp = SredL + p * 4096 + q * 64;
            const int key = q & 15;
            #pragma unroll
            for (int rr = 0; rr < 4; rr++) {
                int u = (mi * 8 + rr * 2 + h) ^ key;
                half4v v4;
                if (ni == 0) {
                    v4[0]=(_Float16)s0[rr*4+0]; v4[1]=(_Float16)s0[rr*4+1];
                    v4[2]=(_Float16)s0[rr*4+2]; v4[3]=(_Float16)s0[rr*4+3];
                } else {
                    v4[0]=(_Float16)s1[rr*4+0]; v4[1]=(_Float16)s1[rr*4+1];
                    v4[2]=(_Float16)s1[rr*4+2]; v4[3]=(_Float16)s1[rr*4+3];
                }
                *(half4v*)&sp[u * 4] = v4;
            }
        }
        // ---- issue kn[t+1] (step1 reads completed via mfma operand waits) ----
        if (t < 63) {
            FENCE();
            #pragma unroll
            for (int i = 0; i < 8; i++) {
                int r = i * 4 + (l >> 4);
                int c = (l & 15) ^ (r & 15);
                const unsigned short* gp = xnb + (size_t)((t+1)*64 + mi*32 + r) * DH + wk0 + c * 8;
                __builtin_amdgcn_global_load_lds(
                    (const __attribute__((address_space(1))) void*)gp,
                    (__attribute__((address_space(3))) void*)&knP[i * 512], 16, 0, 0);
            }
            FENCE();
        }
        WAITLGKM();
        BAR();   // BAR_B: Sred complete

        // ---- reduce: 4 partials x 2 b64 (conflict-free), *V ----
        half4v l0 = *(const half4v*)&SredL[        tq * 64 + aLo];
        half4v h0 = *(const half4v*)&SredL[        tq * 64 + aHi];
        half4v l1 = *(const half4v*)&SredL[4096  + tq * 64 + aLo];
        half4v h1 = *(const half4v*)&SredL[4096  + tq * 64 + aHi];
        half4v l2 = *(const half4v*)&SredL[8192  + tq * 64 + aLo];
        half4v h2 = *(const half4v*)&SredL[8192  + tq * 64 + aHi];
        half4v l3 = *(const half4v*)&SredL[12288 + tq * 64 + aLo];
        half4v h3 = *(const half4v*)&SredL[12288 + tq * 64 + aHi];
        half4v sLo = (l0 + l1) + (l2 + l3);
        half4v sHi = (h0 + h1) + (h2 + h3);
        if (t < 63) { asm volatile("s_waitcnt vmcnt(8)" ::: "memory"); }
        else        { asm volatile("s_waitcnt vmcnt(0)" ::: "memory"); }
        half4v wLo, wHi;
        wLo[0]=(_Float16)((float)sLo[0]*vf0[0]); wLo[1]=(_Float16)((float)sLo[1]*vf0[1]);
        wLo[2]=(_Float16)((float)sLo[2]*vf0[2]); wLo[3]=(_Float16)((float)sLo[3]*vf0[3]);
        wHi[0]=(_Float16)((float)sHi[0]*vf1[0]); wHi[1]=(_Float16)((float)sHi[1]*vf1[1]);
        wHi[2]=(_Float16)((float)sHi[2]*vf1[2]); wHi[3]=(_Float16)((float)sHi[3]*vf1[3]);
        // ---- W write to OWN Sred-p0 addresses (read-then-write same 8B; no WAR) ----
        *(half4v*)&SredL[tq * 64 + aLo] = wLo;
        *(half4v*)&SredL[tq * 64 + aHi] = wHi;
        WAITLGKM();
        BAR();   // BAR_C: W ready

        // ---- step3: ctx[q][wd0..+64] += W * Kn ; W via 2xb64 per frag (conflict-free) ----
        const int keyA = m32 & 15;               // rows m32 and 32+m32 share key
        __builtin_amdgcn_s_setprio(1);
        #pragma unroll
        for (int ks = 0; ks < 4; ks++) {
            const int u0 = ks * 4 + h * 2;
            const int a0 = (u0 ^ keyA) * 4;
            const int a1 = ((u0 + 1) ^ keyA) * 4;
            half8 wf0, wf1;
            *(half4v*)&wf0       = *(const half4v*)&SredL[(m32     ) * 64 + a0];
            *(((half4v*)&wf0)+1) = *(const half4v*)&SredL[(m32     ) * 64 + a1];
            *(half4v*)&wf1       = *(const half4v*)&SredL[(32 + m32) * 64 + a0];
            *(((half4v*)&wf1)+1) = *(const half4v*)&SredL[(32 + m32) * 64 + a1];
            const int ko = ((ks*2 + h) ^ (m32 & 7)) * 8;
            half8 kf0 = *(const half8*)&ktP[(m32     ) * 64 + ko];
            half8 kf1 = *(const half8*)&ktP[(32 + m32) * 64 + ko];
            acc[0][0] = __builtin_amdgcn_mfma_f32_32x32x16_f16(wf0, kf0, acc[0][0], 0, 0, 0);
            acc[0][1] = __builtin_amdgcn_mfma_f32_32x32x16_f16(wf0, kf1, acc[0][1], 0, 0, 0);
            acc[1][0] = __builtin_amdgcn_mfma_f32_32x32x16_f16(wf1, kf0, acc[1][0], 0, 0, 0);
            acc[1][1] = __builtin_amdgcn_mfma_f32_32x32x16_f16(wf1, kf1, acc[1][1], 0, 0, 0);
        }
        __builtin_amdgcn_s_setprio(0);
        // ---- issue kt[t+1] + V[t+1] (step3 kt reads completed via mfma waits) ----
        if (t < 63) {
            FENCE();
            #pragma unroll
            for (int i = 0; i < 8; i++) {
                int dr = i * 8 + (l >> 3);
                int c = (l & 7) ^ (dr & 7);
                const unsigned short* gp = xtb + (size_t)(wd0 + dr) * TT + (t+1)*64 + c * 8;
                __builtin_amdgcn_global_load_lds(
                    (const __attribute__((address_space(1))) void*)gp,
                    (__attribute__((address_space(3))) void*)&ktP[i * 512], 16, 0, 0);
            }
            FENCE();
            vf0 = *(const floatx4*)(vptr + (t+1)*64);
            vf1 = *(const floatx4*)(vptr + (t+1)*64 + 4);
            FENCE();
        }
        WAITLGKM();
        BAR();   // BAR_D: step3 reads done -> Sred/W reusable next tile
    }

    // ---- epilogue: out = x_left * sigmoid(ctx + bias) ----
    const float* xb = x + (size_t)b * TT * 1024;
    float* ob = out + (size_t)b * TT * DH;
    #pragma unroll
    for (int mi2 = 0; mi2 < 2; mi2++)
        #pragma unroll
        for (int nd = 0; nd < 2; nd++) {
            int d = wd0 + nd * 32 + m32;
            float bv = bias[d];
            #pragma unroll
            for (int r = 0; r < 16; r++) {
                int q = q0 + mi2 * 32 + (r & 3) + 8 * (r >> 2) + 4 * h;
                float cv = acc[mi2][nd][r] + bv;
                float gate = 1.0f / (1.0f + __expf(-cv));
                ob[(size_t)q * DH + d] = xb[(size_t)q * 1024 + d] * gate;
            }
        }
}

extern "C" void kernel_launch(void* const* d_in, const int* in_sizes, int n_in,
                              void* d_out, int out_size, void* d_ws, size_t ws_size,
                              hipStream_t stream) {
    const float* x    = (const float*)d_in[0];
    const float* V    = (const float*)d_in[1];
    const float* bias = (const float*)d_in[2];
    float* out = (float*)d_out;

    unsigned short* xn  = (unsigned short*)d_ws;              // [4][4096][512] fp16
    unsigned short* xnT = xn + (size_t)4 * TT * DH;           // [4][512][4096] fp16

    norm_k<<<dim3(4 * TT / 4), 256, 0, stream>>>(x, xn);
    transpose_k<<<dim3(TT / 64, DH / 64, 4), 256, 0, stream>>>(xn, xnT);
    fused_k<<<dim3(TT / 64, 4), 512, 0, stream>>>(xn, xnT, V, bias, x, out);
}

// Round 15
// 189.249 us; speedup vs baseline: 1.0510x; 1.0510x over previous
//
#include <hip/hip_runtime.h>
#include <stdint.h>

typedef _Float16 half8 __attribute__((ext_vector_type(8)));
typedef _Float16 half4v __attribute__((ext_vector_type(4)));
typedef float floatx4 __attribute__((ext_vector_type(4)));
typedef float floatx16 __attribute__((ext_vector_type(16)));
typedef long long i64v;

#define TT 4096
#define DH 512

#define WAITLGKM() asm volatile("s_waitcnt lgkmcnt(0)" ::: "memory")
#define BAR() __builtin_amdgcn_s_barrier()
#define FENCE() asm volatile("" ::: "memory")

__device__ __forceinline__ unsigned short f2h(float f) {
    union { _Float16 h; unsigned short u; } v;
    v.h = (_Float16)f;
    return v.u;
}

// ---------- kernel 1: normalize right half of x -> xn (fp16) + xn8 (e4m3, x16 scale) ----------
__global__ void norm_k(const float* __restrict__ x, unsigned short* __restrict__ xn,
                       unsigned char* __restrict__ xn8) {
    const int w = threadIdx.x >> 6, l = threadIdx.x & 63;
    const int row = blockIdx.x * 4 + w;              // 0 .. B*T-1
    const float* src = x + (size_t)row * 1024 + 512 + l * 8;
    floatx4 a = *(const floatx4*)src;
    floatx4 c = *(const floatx4*)(src + 4);
    float s = a[0]*a[0] + a[1]*a[1] + a[2]*a[2] + a[3]*a[3]
            + c[0]*c[0] + c[1]*c[1] + c[2]*c[2] + c[3]*c[3];
    #pragma unroll
    for (int off = 32; off > 0; off >>= 1) s += __shfl_xor(s, off);
    const float scale = 1.0f / fmaxf(sqrtf(s), 1e-12f);
    float v[8] = {a[0], a[1], a[2], a[3], c[0], c[1], c[2], c[3]};
    uint32_t pk[4];
    #pragma unroll
    for (int i = 0; i < 4; i++)
        pk[i] = (uint32_t)f2h(v[2*i] * scale) | ((uint32_t)f2h(v[2*i+1] * scale) << 16);
    uint4 o; o.x = pk[0]; o.y = pk[1]; o.z = pk[2]; o.w = pk[3];
    *(uint4*)(xn + (size_t)row * DH + l * 8) = o;
    // fp8 e4m3 copy, scaled x16 (S gets x256, folded out at W = V*S/256)
    const float s16 = scale * 16.0f;
    int pa = __builtin_amdgcn_cvt_pk_fp8_f32(v[0]*s16, v[1]*s16, 0, 0);
    pa     = __builtin_amdgcn_cvt_pk_fp8_f32(v[2]*s16, v[3]*s16, pa, 1);
    int pb = __builtin_amdgcn_cvt_pk_fp8_f32(v[4]*s16, v[5]*s16, 0, 0);
    pb     = __builtin_amdgcn_cvt_pk_fp8_f32(v[6]*s16, v[7]*s16, pb, 1);
    uint2 o8; o8.x = (uint32_t)pa; o8.y = (uint32_t)pb;
    *(uint2*)(xn8 + (size_t)row * DH + l * 8) = o8;
}

// ---------- kernel 2: xnT[b][d][t] = xn[b][t][d], 64x64 LDS tile transpose ----------
__global__ void transpose_k(const unsigned short* __restrict__ xn,
                            unsigned short* __restrict__ xnT) {
    __shared__ __align__(16) unsigned short tile[64 * 72];  // +8 pad
    const int b = blockIdx.z;
    const int t0 = blockIdx.x * 64, d0 = blockIdx.y * 64;
    const int tid = threadIdx.x;
    #pragma unroll
    for (int i = 0; i < 2; i++) {
        int c = i * 256 + tid;
        int tr = c >> 3, d8 = c & 7;
        uint4 vv = *(const uint4*)(xn + ((size_t)(b * TT + t0 + tr) * DH + d0 + d8 * 8));
        *(uint4*)&tile[tr * 72 + d8 * 8] = vv;
    }
    __syncthreads();
    #pragma unroll
    for (int i = 0; i < 2; i++) {
        int c = i * 256 + tid;
        int dd = c >> 3, t8 = c & 7;
        uint32_t pk[4];
        #pragma unroll
        for (int k = 0; k < 4; k++) {
            uint32_t h0 = tile[(t8 * 8 + 2 * k    ) * 72 + dd];
            uint32_t h1 = tile[(t8 * 8 + 2 * k + 1) * 72 + dd];
            pk[k] = h0 | (h1 << 16);
        }
        uint4 o; o.x = pk[0]; o.y = pk[1]; o.z = pk[2]; o.w = pk[3];
        *(uint4*)(xnT + ((size_t)(b * DH + d0 + dd) * TT + t0 + t8 * 8)) = o;
    }
}

// ---------- kernel 3: R14 schedule, step1 in fp8 (kn8 staged, Q fp8 regs) ----------
// Wave w: step1 role (g=w>>2, mi=(w>>1)&1, dh=w&1): S^T partial p=g*2+dh over K=128, fp8;
//   step3/epilogue role: d-slice [w*64, w*64+64), fp16.
// kn8 slice [32kk][128B fp8], granule(16B) g stored at g^(kk&7); staged by 4 gll/wave.
// Per tile (3 barriers):
//   vmcnt(10) [kn8(4 oldest) done; kt 8 + V 2 in flight]
//   step1 (8 b64 rd, 16 fp8-mfma) ; Sred wr (b64, ^q&15) ; issue kn8[t+1] ; lgkm ; BAR_B
//   reduce (8 b64) ; vmcnt(4) ; *V/256 ; W wr to OWN addr ; lgkm ; BAR_C
//   step3 (16 b64 W + 8 b128 kt, 16 f16-mfma) ; issue kt[t+1]+V[t+1] ; lgkm ; BAR_D
// LDS 128 KiB: kn8[8w][4KB] 32K | kt[8w][64d][64kk] 64K | Sred[4][64][64] 32K (p0=W).
__global__ __launch_bounds__(512, 2) void fused_k(
    const unsigned char* __restrict__ xn8, const unsigned short* __restrict__ xnT,
    const float* __restrict__ V, const float* __restrict__ bias,
    const float* __restrict__ x, float* __restrict__ out)
{
    __shared__ __align__(16) unsigned short smem[65536];   // 128 KiB
    unsigned char*  kn8B  = (unsigned char*)smem;          // 32 KiB
    unsigned short* ktB   = smem + 16384;                  // 64 KiB
    unsigned short* SredL = smem + 49152;                  // 32 KiB; p0 doubles as W

    const int tid = threadIdx.x;
    const int w = tid >> 6, l = tid & 63;
    const int h = l >> 5, m32 = l & 31;
    const int g = w >> 2, mi = (w >> 1) & 1, dh = w & 1;
    const int p = g * 2 + dh;
    const int wk0 = g * 256 + dh * 128;      // step1 k-range base
    const int wd0 = w * 64;                  // step3 d-slice base

    // XCD-aware swizzle
    const int flat = blockIdx.y * 64 + blockIdx.x;
    const int work = (flat & 7) * 32 + (flat >> 3);
    const int b = work >> 6, qt = work & 63;
    const int q0 = qt * 64;

    const unsigned char*  x8b = xn8 + (size_t)b * TT * DH;
    const unsigned short* xtb = xnT + (size_t)b * DH * TT;

    unsigned char*  knP8 = kn8B + w * 4096;
    unsigned short* ktP  = ktB + w * 4096;

    // reduce-phase mapping: q-row tq, kk chunk to (logical units 2to, 2to+1)
    const int tq = tid >> 3, to = tid & 7;
    const float* vptr = V + (size_t)(q0 + tq) * TT + to * 8;
    const int keyR = tq & 15;
    const int aLo = ((to * 2    ) ^ keyR) * 4;
    const int aHi = ((to * 2 + 1) ^ keyR) * 4;

    // ---- prologue: Q fp8 fragments (B-operand): lane q=q0+ni*32+m32, k=wk0+ks*16+h*8+j
    i64v qf8[2][8];
    #pragma unroll
    for (int ni = 0; ni < 2; ni++)
        #pragma unroll
        for (int ks = 0; ks < 8; ks++)
            qf8[ni][ks] = *(const i64v*)(x8b + (size_t)(q0 + ni*32 + m32) * DH
                                         + wk0 + ks*16 + h*8);
    FENCE();
    // stage kn8[0]: 4 gll, 8 rows each; granule pre-swizzle g^(row&7) at source
    #pragma unroll
    for (int i = 0; i < 4; i++) {
        int r = i * 8 + (l >> 3);                        // local kk row 0..31
        int dg = (l & 7) ^ (r & 7);                      // source granule
        const unsigned char* gp = x8b + (size_t)(mi*32 + r) * DH + wk0 + dg * 16;
        __builtin_amdgcn_global_load_lds(
            (const __attribute__((address_space(1))) void*)gp,
            (__attribute__((address_space(3))) void*)&knP8[i * 1024], 16, 0, 0);
    }
    FENCE();
    // stage kt[0]: 8 gll, 8 d-rows each
    #pragma unroll
    for (int i = 0; i < 8; i++) {
        int dr = i * 8 + (l >> 3);                       // local d row 0..63
        int c = (l & 7) ^ (dr & 7);
        const unsigned short* gp = xtb + (size_t)(wd0 + dr) * TT + c * 8;
        __builtin_amdgcn_global_load_lds(
            (const __attribute__((address_space(1))) void*)gp,
            (__attribute__((address_space(3))) void*)&ktP[i * 512], 16, 0, 0);
    }
    FENCE();
    floatx4 vf0 = *(const floatx4*)(vptr);
    floatx4 vf1 = *(const floatx4*)(vptr + 4);

    floatx16 acc[2][2];
    #pragma unroll
    for (int i = 0; i < 2; i++)
        #pragma unroll
        for (int j = 0; j < 2; j++)
            acc[i][j] = (floatx16)(0.f);

    #pragma unroll 1
    for (int t = 0; t < 64; t++) {
        // ---- kn8[t] landed (kt[t] 8 + V[t] 2 stay in flight) ----
        asm volatile("s_waitcnt vmcnt(10)" ::: "memory");

        // ---- step1 (fp8): S^T partial p, rows mi, k-128; 8 b64 reads, 16 mfma ----
        floatx16 s0 = (floatx16)(0.f), s1 = (floatx16)(0.f);
        __builtin_amdgcn_s_setprio(1);
        #pragma unroll
        for (int ks = 0; ks < 8; ks++) {
            i64v a8 = *(const i64v*)&knP8[m32 * 128 + ((ks ^ (m32 & 7)) * 16) + h * 8];
            s0 = __builtin_amdgcn_mfma_f32_32x32x16_fp8_fp8(a8, qf8[0][ks], s0, 0, 0, 0);
            s1 = __builtin_amdgcn_mfma_f32_32x32x16_fp8_fp8(a8, qf8[1][ks], s1, 0, 0, 0);
        }
        __builtin_amdgcn_s_setprio(0);

        // ---- Sred write: [p][q][unit u ^ (q&15)], b64 ----
        #pragma unroll
        for (int ni = 0; ni < 2; ni++) {
            const int q = ni * 32 + m32;
            unsigned short* sp = SredL + p * 4096 + q * 64;
            const int key = q & 15;
            #pragma unroll
            for (int rr = 0; rr < 4; rr++) {
                int u = (mi * 8 + rr * 2 + h) ^ key;
                half4v v4;
                if (ni == 0) {
                    v4[0]=(_Float16)s0[rr*4+0]; v4[1]=(_Float16)s0[rr*4+1];
                    v4[2]=(_Float16)s0[rr*4+2]; v4[3]=(_Float16)s0[rr*4+3];
                } else {
                    v4[0]=(_Float16)s1[rr*4+0]; v4[1]=(_Float16)s1[rr*4+1];
                    v4[2]=(_Float16)s1[rr*4+2]; v4[3]=(_Float16)s1[rr*4+3];
                }
                *(half4v*)&sp[u * 4] = v4;
            }
        }
        // ---- issue kn8[t+1] ----
        if (t < 63) {
            FENCE();
            #pragma unroll
            for (int i = 0; i < 4; i++) {
                int r = i * 8 + (l >> 3);
                int dg = (l & 7) ^ (r & 7);
                const unsigned char* gp = x8b + (size_t)((t+1)*64 + mi*32 + r) * DH + wk0 + dg * 16;
                __builtin_amdgcn_global_load_lds(
                    (const __attribute__((address_space(1))) void*)gp,
                    (__attribute__((address_space(3))) void*)&knP8[i * 1024], 16, 0, 0);
            }
            FENCE();
        }
        WAITLGKM();
        BAR();   // BAR_B: Sred complete

        // ---- reduce: 4 partials x 2 b64, *V/256 ----
        half4v l0 = *(const half4v*)&SredL[        tq * 64 + aLo];
        half4v h0 = *(const half4v*)&SredL[        tq * 64 + aHi];
        half4v l1 = *(const half4v*)&SredL[4096  + tq * 64 + aLo];
        half4v h1 = *(const half4v*)&SredL[4096  + tq * 64 + aHi];
        half4v l2 = *(const half4v*)&SredL[8192  + tq * 64 + aLo];
        half4v h2 = *(const half4v*)&SredL[8192  + tq * 64 + aHi];
        half4v l3 = *(const half4v*)&SredL[12288 + tq * 64 + aLo];
        half4v h3 = *(const half4v*)&SredL[12288 + tq * 64 + aHi];
        half4v sLo = (l0 + l1) + (l2 + l3);
        half4v sHi = (h0 + h1) + (h2 + h3);
        if (t < 63) { asm volatile("s_waitcnt vmcnt(4)" ::: "memory"); }
        else        { asm volatile("s_waitcnt vmcnt(0)" ::: "memory"); }
        const float is = 1.0f / 256.0f;
        half4v wLo, wHi;
        wLo[0]=(_Float16)((float)sLo[0]*vf0[0]*is); wLo[1]=(_Float16)((float)sLo[1]*vf0[1]*is);
        wLo[2]=(_Float16)((float)sLo[2]*vf0[2]*is); wLo[3]=(_Float16)((float)sLo[3]*vf0[3]*is);
        wHi[0]=(_Float16)((float)sHi[0]*vf1[0]*is); wHi[1]=(_Float16)((float)sHi[1]*vf1[1]*is);
        wHi[2]=(_Float16)((float)sHi[2]*vf1[2]*is); wHi[3]=(_Float16)((float)sHi[3]*vf1[3]*is);
        // ---- W write to OWN Sred-p0 addresses ----
        *(half4v*)&SredL[tq * 64 + aLo] = wLo;
        *(half4v*)&SredL[tq * 64 + aHi] = wHi;
        WAITLGKM();
        BAR();   // BAR_C: W ready

        // ---- step3 (fp16): ctx[q][wd0..+64] += W * Kn ----
        const int keyA = m32 & 15;
        __builtin_amdgcn_s_setprio(1);
        #pragma unroll
        for (int ks = 0; ks < 4; ks++) {
            const int u0 = ks * 4 + h * 2;
            const int a0 = (u0 ^ keyA) * 4;
            const int a1 = ((u0 + 1) ^ keyA) * 4;
            half8 wf0, wf1;
            *(half4v*)&wf0       = *(const half4v*)&SredL[(m32     ) * 64 + a0];
            *(((half4v*)&wf0)+1) = *(const half4v*)&SredL[(m32     ) * 64 + a1];
            *(half4v*)&wf1       = *(const half4v*)&SredL[(32 + m32) * 64 + a0];
            *(((half4v*)&wf1)+1) = *(const half4v*)&SredL[(32 + m32) * 64 + a1];
            const int ko = ((ks*2 + h) ^ (m32 & 7)) * 8;
            half8 kf0 = *(const half8*)&ktP[(m32     ) * 64 + ko];
            half8 kf1 = *(const half8*)&ktP[(32 + m32) * 64 + ko];
            acc[0][0] = __builtin_amdgcn_mfma_f32_32x32x16_f16(wf0, kf0, acc[0][0], 0, 0, 0);
            acc[0][1] = __builtin_amdgcn_mfma_f32_32x32x16_f16(wf0, kf1, acc[0][1], 0, 0, 0);
            acc[1][0] = __builtin_amdgcn_mfma_f32_32x32x16_f16(wf1, kf0, acc[1][0], 0, 0, 0);
            acc[1][1] = __builtin_amdgcn_mfma_f32_32x32x16_f16(wf1, kf1, acc[1][1], 0, 0, 0);
        }
        __builtin_amdgcn_s_setprio(0);
        // ---- issue kt[t+1] + V[t+1] ----
        if (t < 63) {
            FENCE();
            #pragma unroll
            for (int i = 0; i < 8; i++) {
                int dr = i * 8 + (l >> 3);
                int c = (l & 7) ^ (dr & 7);
                const unsigned short* gp = xtb + (size_t)(wd0 + dr) * TT + (t+1)*64 + c * 8;
                __builtin_amdgcn_global_load_lds(
                    (const __attribute__((address_space(1))) void*)gp,
                    (__attribute__((address_space(3))) void*)&ktP[i * 512], 16, 0, 0);
            }
            FENCE();
            vf0 = *(const floatx4*)(vptr + (t+1)*64);
            vf1 = *(const floatx4*)(vptr + (t+1)*64 + 4);
            FENCE();
        }
        WAITLGKM();
        BAR();   // BAR_D: step3 reads done -> Sred/W reusable next tile
    }

    // ---- epilogue: out = x_left * sigmoid(ctx + bias) ----
    const float* xb = x + (size_t)b * TT * 1024;
    float* ob = out + (size_t)b * TT * DH;
    #pragma unroll
    for (int mi2 = 0; mi2 < 2; mi2++)
        #pragma unroll
        for (int nd = 0; nd < 2; nd++) {
            int d = wd0 + nd * 32 + m32;
            float bv = bias[d];
            #pragma unroll
            for (int r = 0; r < 16; r++) {
                int q = q0 + mi2 * 32 + (r & 3) + 8 * (r >> 2) + 4 * h;
                float cv = acc[mi2][nd][r] + bv;
                float gate = 1.0f / (1.0f + __expf(-cv));
                ob[(size_t)q * DH + d] = xb[(size_t)q * 1024 + d] * gate;
            }
        }
}

extern "C" void kernel_launch(void* const* d_in, const int* in_sizes, int n_in,
                              void* d_out, int out_size, void* d_ws, size_t ws_size,
                              hipStream_t stream) {
    const float* x    = (const float*)d_in[0];
    const float* V    = (const float*)d_in[1];
    const float* bias = (const float*)d_in[2];
    float* out = (float*)d_out;

    unsigned short* xn  = (unsigned short*)d_ws;                    // [4][4096][512] fp16, 16MB
    unsigned short* xnT = xn + (size_t)4 * TT * DH;                 // [4][512][4096] fp16, 16MB
    unsigned char*  xn8 = (unsigned char*)(xnT + (size_t)4 * DH * TT); // [4][4096][512] fp8, 8MB

    norm_k<<<dim3(4 * TT / 4), 256, 0, stream>>>(x, xn, xn8);
    transpose_k<<<dim3(TT / 64, DH / 64, 4), 256, 0, stream>>>(xn, xnT);
    fused_k<<<dim3(TT / 64, 4), 512, 0, stream>>>(xn8, xnT, V, bias, x, out);
}

// Round 16
// 159.187 us; speedup vs baseline: 1.2495x; 1.1888x over previous
//
#include <hip/hip_runtime.h>
#include <stdint.h>

typedef _Float16 half8 __attribute__((ext_vector_type(8)));
typedef _Float16 half4v __attribute__((ext_vector_type(4)));
typedef float floatx4 __attribute__((ext_vector_type(4)));
typedef float floatx16 __attribute__((ext_vector_type(16)));
typedef long long i64v;

#define TT 4096
#define DH 512

#define WAITLGKM() asm volatile("s_waitcnt lgkmcnt(0)" ::: "memory")
#define BAR() __builtin_amdgcn_s_barrier()
#define FENCE() asm volatile("" ::: "memory")

__device__ __forceinline__ unsigned short f2h(float f) {
    union { _Float16 h; unsigned short u; } v;
    v.h = (_Float16)f;
    return v.u;
}

// ---------- kernel 1: normalize right half of x -> xn (fp16) + xn8 (e4m3, x16 scale) ----------
__global__ void norm_k(const float* __restrict__ x, unsigned short* __restrict__ xn,
                       unsigned char* __restrict__ xn8) {
    const int w = threadIdx.x >> 6, l = threadIdx.x & 63;
    const int row = blockIdx.x * 4 + w;              // 0 .. B*T-1
    const float* src = x + (size_t)row * 1024 + 512 + l * 8;
    floatx4 a = *(const floatx4*)src;
    floatx4 c = *(const floatx4*)(src + 4);
    float s = a[0]*a[0] + a[1]*a[1] + a[2]*a[2] + a[3]*a[3]
            + c[0]*c[0] + c[1]*c[1] + c[2]*c[2] + c[3]*c[3];
    #pragma unroll
    for (int off = 32; off > 0; off >>= 1) s += __shfl_xor(s, off);
    const float scale = 1.0f / fmaxf(sqrtf(s), 1e-12f);
    float v[8] = {a[0], a[1], a[2], a[3], c[0], c[1], c[2], c[3]};
    uint32_t pk[4];
    #pragma unroll
    for (int i = 0; i < 4; i++)
        pk[i] = (uint32_t)f2h(v[2*i] * scale) | ((uint32_t)f2h(v[2*i+1] * scale) << 16);
    uint4 o; o.x = pk[0]; o.y = pk[1]; o.z = pk[2]; o.w = pk[3];
    *(uint4*)(xn + (size_t)row * DH + l * 8) = o;
    // fp8 e4m3 copy, scaled x16
    const float s16 = scale * 16.0f;
    int pa = __builtin_amdgcn_cvt_pk_fp8_f32(v[0]*s16, v[1]*s16, 0, 0);
    pa     = __builtin_amdgcn_cvt_pk_fp8_f32(v[2]*s16, v[3]*s16, pa, 1);
    int pb = __builtin_amdgcn_cvt_pk_fp8_f32(v[4]*s16, v[5]*s16, 0, 0);
    pb     = __builtin_amdgcn_cvt_pk_fp8_f32(v[6]*s16, v[7]*s16, pb, 1);
    uint2 o8; o8.x = (uint32_t)pa; o8.y = (uint32_t)pb;
    *(uint2*)(xn8 + (size_t)row * DH + l * 8) = o8;
}

// ---------- kernel 2: xnT8[b][d][t] = fp8(xn[b][t][d] * 16), 64x64 LDS tile transpose ----------
__global__ void transpose_k(const unsigned short* __restrict__ xn,
                            unsigned char* __restrict__ xnT8) {
    __shared__ __align__(16) unsigned short tile[64 * 72];  // +8 pad
    const int b = blockIdx.z;
    const int t0 = blockIdx.x * 64, d0 = blockIdx.y * 64;
    const int tid = threadIdx.x;
    #pragma unroll
    for (int i = 0; i < 2; i++) {
        int c = i * 256 + tid;
        int tr = c >> 3, d8 = c & 7;
        uint4 vv = *(const uint4*)(xn + ((size_t)(b * TT + t0 + tr) * DH + d0 + d8 * 8));
        *(uint4*)&tile[tr * 72 + d8 * 8] = vv;
    }
    __syncthreads();
    #pragma unroll
    for (int i = 0; i < 2; i++) {
        int c = i * 256 + tid;
        int dd = c >> 3, t8 = c & 7;
        float f[8];
        #pragma unroll
        for (int k = 0; k < 8; k++) {
            unsigned short u = tile[(t8 * 8 + k) * 72 + dd];
            f[k] = (float)(*(const _Float16*)&u) * 16.0f;
        }
        int pa = __builtin_amdgcn_cvt_pk_fp8_f32(f[0], f[1], 0, 0);
        pa     = __builtin_amdgcn_cvt_pk_fp8_f32(f[2], f[3], pa, 1);
        int pb = __builtin_amdgcn_cvt_pk_fp8_f32(f[4], f[5], 0, 0);
        pb     = __builtin_amdgcn_cvt_pk_fp8_f32(f[6], f[7], pb, 1);
        uint2 o8; o8.x = (uint32_t)pa; o8.y = (uint32_t)pb;
        *(uint2*)(xnT8 + ((size_t)(b * DH + d0 + dd) * TT + t0 + t8 * 8)) = o8;
    }
}

// ---------- kernel 3: R15 schedule, BOTH matmuls in fp8 ----------
// Wave w: step1 role (g=w>>2, mi=(w>>1)&1, dh=w&1): S^T partial p=g*2+dh over K=128, fp8;
//   step3/epilogue role: d-slice [w*64, w*64+64), fp8 (W8 = S256*V, kt8 = KnT*16; acc x4096).
// Per tile (3 barriers):
//   vmcnt(6) [kn8 landed; kt8 4 + V 2 in flight]
//   step1 (8 b64 rd, 16 fp8-mfma) ; Sred wr fp16 (b64, ^q&15) ; issue kn8[t+1] ; lgkm ; BAR_B
//   reduce (8 b64) ; vmcnt(4) ; W8 = fp8(S256*V) wr to OWN bytes ; lgkm ; BAR_C
//   step3 (8 b64 W8 + 8 b64 kt8, 16 fp8-mfma) ; issue kt8[t+1]+V[t+1] ; lgkm ; BAR_D
// LDS 96 KiB: kn8[8w][4KB] 32K | kt8[8w][4KB] 32K | Sred[4][64][64]f16 32K (p0 bytes = W8).
__global__ __launch_bounds__(512, 2) void fused_k(
    const unsigned char* __restrict__ xn8, const unsigned char* __restrict__ xnT8,
    const float* __restrict__ V, const float* __restrict__ bias,
    const float* __restrict__ x, float* __restrict__ out)
{
    __shared__ __align__(16) unsigned char smemB[98304];   // 96 KiB
    unsigned char*  kn8B  = smemB;                          // 32 KiB
    unsigned char*  kt8B  = smemB + 32768;                  // 32 KiB
    unsigned short* SredL = (unsigned short*)(smemB + 65536); // 32 KiB fp16; p0 bytes = W8

    const int tid = threadIdx.x;
    const int w = tid >> 6, l = tid & 63;
    const int h = l >> 5, m32 = l & 31;
    const int g = w >> 2, mi = (w >> 1) & 1, dh = w & 1;
    const int p = g * 2 + dh;
    const int wk0 = g * 256 + dh * 128;      // step1 k-range base
    const int wd0 = w * 64;                  // step3 d-slice base

    // XCD-aware swizzle
    const int flat = blockIdx.y * 64 + blockIdx.x;
    const int work = (flat & 7) * 32 + (flat >> 3);
    const int b = work >> 6, qt = work & 63;
    const int q0 = qt * 64;

    const unsigned char* x8b = xn8  + (size_t)b * TT * DH;
    const unsigned char* xt8 = xnT8 + (size_t)b * DH * TT;

    unsigned char* knP8 = kn8B + w * 4096;
    unsigned char* ktP8 = kt8B + w * 4096;

    // reduce-phase mapping: q-row tq, kk group to (8 kk); W8 byte addr shares Sred aLo bytes
    const int tq = tid >> 3, to = tid & 7;
    const float* vptr = V + (size_t)(q0 + tq) * TT + to * 8;
    const int keyR = tq & 15;
    const int aLo = ((to * 2    ) ^ keyR) * 4;   // phys half-offset of logical unit 2to
    const int aHi = ((to * 2 + 1) ^ keyR) * 4;

    // ---- prologue: Q fp8 fragments (B-operand): lane q=q0+ni*32+m32
    i64v qf8[2][8];
    #pragma unroll
    for (int ni = 0; ni < 2; ni++)
        #pragma unroll
        for (int ks = 0; ks < 8; ks++)
            qf8[ni][ks] = *(const i64v*)(x8b + (size_t)(q0 + ni*32 + m32) * DH
                                         + wk0 + ks*16 + h*8);
    FENCE();
    // stage kn8[0]: 4 gll, 8 rows each; 16B-chunk pre-swizzle c^(row&7)
    #pragma unroll
    for (int i = 0; i < 4; i++) {
        int r = i * 8 + (l >> 3);
        int dg = (l & 7) ^ (r & 7);
        const unsigned char* gp = x8b + (size_t)(mi*32 + r) * DH + wk0 + dg * 16;
        __builtin_amdgcn_global_load_lds(
            (const __attribute__((address_space(1))) void*)gp,
            (__attribute__((address_space(3))) void*)&knP8[i * 1024], 16, 0, 0);
    }
    FENCE();
    // stage kt8[0]: 4 gll, 16 d-rows each; 16B-chunk pre-swizzle c^((row>>1)&3)
    #pragma unroll
    for (int i = 0; i < 4; i++) {
        int dr = i * 16 + (l >> 2);
        int cs = (l & 3) ^ ((dr >> 1) & 3);
        const unsigned char* gp = xt8 + (size_t)(wd0 + dr) * TT + cs * 16;
        __builtin_amdgcn_global_load_lds(
            (const __attribute__((address_space(1))) void*)gp,
            (__attribute__((address_space(3))) void*)&ktP8[i * 1024], 16, 0, 0);
    }
    FENCE();
    floatx4 vf0 = *(const floatx4*)(vptr);
    floatx4 vf1 = *(const floatx4*)(vptr + 4);

    floatx16 acc[2][2];
    #pragma unroll
    for (int i = 0; i < 2; i++)
        #pragma unroll
        for (int j = 0; j < 2; j++)
            acc[i][j] = (floatx16)(0.f);

    #pragma unroll 1
    for (int t = 0; t < 64; t++) {
        // ---- kn8[t] landed (kt8[t] 4 + V[t] 2 stay in flight) ----
        asm volatile("s_waitcnt vmcnt(6)" ::: "memory");

        // ---- step1 (fp8): S^T partial p, rows mi; 8 b64 reads, 16 mfma ----
        floatx16 s0 = (floatx16)(0.f), s1 = (floatx16)(0.f);
        __builtin_amdgcn_s_setprio(1);
        #pragma unroll
        for (int ks = 0; ks < 8; ks++) {
            i64v a8 = *(const i64v*)&knP8[m32 * 128 + ((ks ^ (m32 & 7)) * 16) + h * 8];
            s0 = __builtin_amdgcn_mfma_f32_32x32x16_fp8_fp8(a8, qf8[0][ks], s0, 0, 0, 0);
            s1 = __builtin_amdgcn_mfma_f32_32x32x16_fp8_fp8(a8, qf8[1][ks], s1, 0, 0, 0);
        }
        __builtin_amdgcn_s_setprio(0);

        // ---- Sred write (fp16): [p][q][unit u ^ (q&15)], b64 ----
        #pragma unroll
        for (int ni = 0; ni < 2; ni++) {
            const int q = ni * 32 + m32;
            unsigned short* sp = SredL + p * 4096 + q * 64;
            const int key = q & 15;
            #pragma unroll
            for (int rr = 0; rr < 4; rr++) {
                int u = (mi * 8 + rr * 2 + h) ^ key;
                half4v v4;
                if (ni == 0) {
                    v4[0]=(_Float16)s0[rr*4+0]; v4[1]=(_Float16)s0[rr*4+1];
                    v4[2]=(_Float16)s0[rr*4+2]; v4[3]=(_Float16)s0[rr*4+3];
                } else {
                    v4[0]=(_Float16)s1[rr*4+0]; v4[1]=(_Float16)s1[rr*4+1];
                    v4[2]=(_Float16)s1[rr*4+2]; v4[3]=(_Float16)s1[rr*4+3];
                }
                *(half4v*)&sp[u * 4] = v4;
            }
        }
        // ---- issue kn8[t+1] ----
        if (t < 63) {
            FENCE();
            #pragma unroll
            for (int i = 0; i < 4; i++) {
                int r = i * 8 + (l >> 3);
                int dg = (l & 7) ^ (r & 7);
                const unsigned char* gp = x8b + (size_t)((t+1)*64 + mi*32 + r) * DH + wk0 + dg * 16;
                __builtin_amdgcn_global_load_lds(
                    (const __attribute__((address_space(1))) void*)gp,
                    (__attribute__((address_space(3))) void*)&knP8[i * 1024], 16, 0, 0);
            }
            FENCE();
        }
        WAITLGKM();
        BAR();   // BAR_B: Sred complete

        // ---- reduce: 4 partials x 2 b64 (fp16), then W8 = fp8(S256 * V) ----
        half4v l0 = *(const half4v*)&SredL[        tq * 64 + aLo];
        half4v h0 = *(const half4v*)&SredL[        tq * 64 + aHi];
        half4v l1 = *(const half4v*)&SredL[4096  + tq * 64 + aLo];
        half4v h1 = *(const half4v*)&SredL[4096  + tq * 64 + aHi];
        half4v l2 = *(const half4v*)&SredL[8192  + tq * 64 + aLo];
        half4v h2 = *(const half4v*)&SredL[8192  + tq * 64 + aHi];
        half4v l3 = *(const half4v*)&SredL[12288 + tq * 64 + aLo];
        half4v h3 = *(const half4v*)&SredL[12288 + tq * 64 + aHi];
        half4v sLo = (l0 + l1) + (l2 + l3);
        half4v sHi = (h0 + h1) + (h2 + h3);
        if (t < 63) { asm volatile("s_waitcnt vmcnt(4)" ::: "memory"); }
        else        { asm volatile("s_waitcnt vmcnt(0)" ::: "memory"); }
        {
            float w0 = (float)sLo[0]*vf0[0], w1 = (float)sLo[1]*vf0[1];
            float w2 = (float)sLo[2]*vf0[2], w3 = (float)sLo[3]*vf0[3];
            float w4 = (float)sHi[0]*vf1[0], w5 = (float)sHi[1]*vf1[1];
            float w6 = (float)sHi[2]*vf1[2], w7 = (float)sHi[3]*vf1[3];
            int pa = __builtin_amdgcn_cvt_pk_fp8_f32(w0, w1, 0, 0);
            pa     = __builtin_amdgcn_cvt_pk_fp8_f32(w2, w3, pa, 1);
            int pb = __builtin_amdgcn_cvt_pk_fp8_f32(w4, w5, 0, 0);
            pb     = __builtin_amdgcn_cvt_pk_fp8_f32(w6, w7, pb, 1);
            uint2 w8w; w8w.x = (uint32_t)pa; w8w.y = (uint32_t)pb;
            // own-bytes overlay: bytes of fp16 unit aLo (8B this thread just read)
            *(uint2*)((unsigned char*)SredL + tq * 128 + ((2*to) ^ keyR) * 8) = w8w;
        }
        WAITLGKM();
        BAR();   // BAR_C: W8 ready

        // ---- step3 (fp8): ctx[q][wd0..+64] += W8 * Kt8 ; acc = 4096*ctx ----
        const unsigned char* W8 = (const unsigned char*)SredL;
        const int keyA = m32 & 15;
        const int k2 = (m32 >> 1) & 3;
        __builtin_amdgcn_s_setprio(1);
        #pragma unroll
        for (int ks = 0; ks < 4; ks++) {
            const int u0 = ks * 4 + h * 2;           // logical 8-byte W group = 2j
            i64v wf0 = *(const i64v*)&W8[(m32     ) * 128 + ((u0 ^ keyA) * 8)];
            i64v wf1 = *(const i64v*)&W8[(32 + m32) * 128 + ((u0 ^ keyA) * 8)];
            const int ko = ((ks ^ k2) * 16) + h * 8;
            i64v kf0 = *(const i64v*)&ktP8[(m32     ) * 64 + ko];
            i64v kf1 = *(const i64v*)&ktP8[(32 + m32) * 64 + ko];
            acc[0][0] = __builtin_amdgcn_mfma_f32_32x32x16_fp8_fp8(wf0, kf0, acc[0][0], 0, 0, 0);
            acc[0][1] = __builtin_amdgcn_mfma_f32_32x32x16_fp8_fp8(wf0, kf1, acc[0][1], 0, 0, 0);
            acc[1][0] = __builtin_amdgcn_mfma_f32_32x32x16_fp8_fp8(wf1, kf0, acc[1][0], 0, 0, 0);
            acc[1][1] = __builtin_amdgcn_mfma_f32_32x32x16_fp8_fp8(wf1, kf1, acc[1][1], 0, 0, 0);
        }
        __builtin_amdgcn_s_setprio(0);
        // ---- issue kt8[t+1] + V[t+1] ----
        if (t < 63) {
            FENCE();
            #pragma unroll
            for (int i = 0; i < 4; i++) {
                int dr = i * 16 + (l >> 2);
                int cs = (l & 3) ^ ((dr >> 1) & 3);
                const unsigned char* gp = xt8 + (size_t)(wd0 + dr) * TT + (t+1)*64 + cs * 16;
                __builtin_amdgcn_global_load_lds(
                    (const __attribute__((address_space(1))) void*)gp,
                    (__attribute__((address_space(3))) void*)&ktP8[i * 1024], 16, 0, 0);
            }
            FENCE();
            vf0 = *(const floatx4*)(vptr + (t+1)*64);
            vf1 = *(const floatx4*)(vptr + (t+1)*64 + 4);
            FENCE();
        }
        WAITLGKM();
        BAR();   // BAR_D: step3 reads done -> Sred/W8 reusable next tile
    }

    // ---- epilogue: out = x_left * sigmoid(ctx/4096 + bias) ----
    const float* xb = x + (size_t)b * TT * 1024;
    float* ob = out + (size_t)b * TT * DH;
    const float isc = 1.0f / 4096.0f;
    #pragma unroll
    for (int mi2 = 0; mi2 < 2; mi2++)
        #pragma unroll
        for (int nd = 0; nd < 2; nd++) {
            int d = wd0 + nd * 32 + m32;
            float bv = bias[d];
            #pragma unroll
            for (int r = 0; r < 16; r++) {
                int q = q0 + mi2 * 32 + (r & 3) + 8 * (r >> 2) + 4 * h;
                float cv = acc[mi2][nd][r] * isc + bv;
                float gate = 1.0f / (1.0f + __expf(-cv));
                ob[(size_t)q * DH + d] = xb[(size_t)q * 1024 + d] * gate;
            }
        }
}

extern "C" void kernel_launch(void* const* d_in, const int* in_sizes, int n_in,
                              void* d_out, int out_size, void* d_ws, size_t ws_size,
                              hipStream_t stream) {
    const float* x    = (const float*)d_in[0];
    const float* V    = (const float*)d_in[1];
    const float* bias = (const float*)d_in[2];
    float* out = (float*)d_out;

    unsigned short* xn   = (unsigned short*)d_ws;                   // [4][4096][512] fp16, 16MB
    unsigned char*  xn8  = (unsigned char*)(xn + (size_t)4 * TT * DH);  // fp8, 8MB
    unsigned char*  xnT8 = xn8 + (size_t)4 * TT * DH;               // [4][512][4096] fp8, 8MB

    norm_k<<<dim3(4 * TT / 4), 256, 0, stream>>>(x, xn, xn8);
    transpose_k<<<dim3(TT / 64, DH / 64, 4), 256, 0, stream>>>(xn, xnT8);
    fused_k<<<dim3(TT / 64, 4), 512, 0, stream>>>(xn8, xnT8, V, bias, x, out);
}